// Round 6
// baseline (444.505 us; speedup 1.0000x reference)
//
#include <hip/hip_runtime.h>
#include <math.h>

#define NLAB 8
#define BATCH 16
// acc layout per batch (floats):
//   [0..27] emb sums L1..7 x4ch | [28..34] cnt_k L1..7 | [35..40] cnt_i L2..7
//   [41..46] agg sums L2..7
#define S_OFF  0
#define CK_OFF 28
#define CI_OFF 35
#define AG_OFF 41
#define ACC_PER_B 48
#define CNT1_IDX (BATCH * ACC_PER_B)       // acc[768]: phase-1 arrival counter
#define CNT2_IDX (BATCH * ACC_PER_B + 1)   // acc[769]: phase-2 arrival counter
#define ACC_ZERO_BYTES ((BATCH * ACC_PER_B + 2) * 4)
#define GX 64                              // 64 x 16 = 1024 blocks = 4/CU EXACT FIT
#define MAXK 8                             // LDS label capacity: 8 tiles per block

__device__ __forceinline__ float wave_reduce(float v) {
#pragma unroll
  for (int off = 32; off > 0; off >>= 1) v += __shfl_xor(v, off, 64);
  return v;
}

// ---------------------------------------------------------------------------
// Fully fused: phase 1 (segment sums) -> software grid barrier -> phase 2
// (aggregation vs mu) -> last-block finalize. One kernel:
//  * labels live in per-block LDS (each block revisits its OWN pixels in
//    phase 2) -> zero global label traffic (R3-R5 paid a 13 MB round-trip)
//  * phase 2 re-reads only emb, with the shortest possible gap after phase 1
//    streamed it -> best shot at L3 hits (two-kernel version got ~none)
//  * one launch instead of two.
// Co-residency for the barrier is guaranteed by exact fit: 1024 blocks,
// __launch_bounds__(256,4) caps VGPR<=128 -> 4 blocks/CU, LDS ~8.3KB << 40KB.
// All global atomics on the main path are issued by wave 0 in program order
// before wave 0's release-arrive (release orders same-wave prior ops).
// ---------------------------------------------------------------------------
__global__ __launch_bounds__(256, 4) void k_fused(
    const float4* __restrict__ emb, const int* __restrict__ inst,
    const float* __restrict__ ker, const float* __restrict__ tmk,
    float* __restrict__ acc, float* __restrict__ out,
    int P, int nblocks)
{
  __shared__ unsigned char labL[MAXK * 1024];  // labels for this block's tiles
  __shared__ float redf[4][28];
  __shared__ int   redi[4][13];
  __shared__ float accL[ACC_PER_B];
  __shared__ float4 smu_s[NLAB];
  __shared__ float redg[4][6];

  const int b = blockIdx.y;
  const size_t base = (size_t)b * P;
  const float4* e  = emb + base;
  const int*    ip = inst + base;
  const float*  kp = ker + base;
  const float*  tp = tmk + base;

  const int lane = threadIdx.x & 63;
  const int wid  = threadIdx.x >> 6;
  const int ntiles = P >> 10;                  // 1024-px tiles
  const int tail = P - (ntiles << 10);

  // ===================== phase 1: segment sums =====================
  float s[28];
#pragma unroll
  for (int k = 0; k < 28; ++k) s[k] = 0.f;
  int ck[7] = {0, 0, 0, 0, 0, 0, 0};
  int ci[6] = {0, 0, 0, 0, 0, 0};

  {
    int k = 0;
    for (int t = blockIdx.x; t < ntiles; t += GX, ++k) {
      const int p0 = (t << 10) + (wid << 8) + lane;
      float4 e0 = e[p0];
      float4 e1 = e[p0 + 64];
      float4 e2 = e[p0 + 128];
      float4 e3 = e[p0 + 192];
      int   v0 = ip[p0], v1 = ip[p0 + 64], v2 = ip[p0 + 128], v3 = ip[p0 + 192];
      float q0 = kp[p0], q1 = kp[p0 + 64], q2 = kp[p0 + 128], q3 = kp[p0 + 192];
      float u0 = tp[p0], u1 = tp[p0 + 64], u2 = tp[p0 + 128], u3 = tp[p0 + 192];

      int lab0 = (u0 > 0.5f) ? (v0 & 7) : 0;
      int lab1 = (u1 > 0.5f) ? (v1 & 7) : 0;
      int lab2 = (u2 > 0.5f) ? (v2 & 7) : 0;
      int lab3 = (u3 > 0.5f) ? (v3 & 7) : 0;
      if (k < MAXK) {
        const int lo = (k << 10) + (wid << 8) + lane;
        labL[lo]       = (unsigned char)lab0;
        labL[lo + 64]  = (unsigned char)lab1;
        labL[lo + 128] = (unsigned char)lab2;
        labL[lo + 192] = (unsigned char)lab3;
      }
      int lk0 = (q0 > 0.5f) ? lab0 : 8;        // 8 = sentinel, matches no l
      int lk1 = (q1 > 0.5f) ? lab1 : 8;
      int lk2 = (q2 > 0.5f) ? lab2 : 8;
      int lk3 = (q3 > 0.5f) ? lab3 : 8;

#pragma unroll
      for (int l = 1; l < NLAB; ++l) {
        bool h0 = (lk0 == l), h1 = (lk1 == l), h2 = (lk2 == l), h3 = (lk3 == l);
        ck[l - 1] += __popcll(__ballot(h0)) + __popcll(__ballot(h1)) +
                     __popcll(__ballot(h2)) + __popcll(__ballot(h3));
        float m0 = h0 ? 1.f : 0.f, m1 = h1 ? 1.f : 0.f;
        float m2 = h2 ? 1.f : 0.f, m3 = h3 ? 1.f : 0.f;
        const int o = (l - 1) * 4;
        s[o + 0] = fmaf(m0, e0.x, fmaf(m1, e1.x, fmaf(m2, e2.x, fmaf(m3, e3.x, s[o + 0]))));
        s[o + 1] = fmaf(m0, e0.y, fmaf(m1, e1.y, fmaf(m2, e2.y, fmaf(m3, e3.y, s[o + 1]))));
        s[o + 2] = fmaf(m0, e0.z, fmaf(m1, e1.z, fmaf(m2, e2.z, fmaf(m3, e3.z, s[o + 2]))));
        s[o + 3] = fmaf(m0, e0.w, fmaf(m1, e1.w, fmaf(m2, e2.w, fmaf(m3, e3.w, s[o + 3]))));
      }
#pragma unroll
      for (int l = 2; l < NLAB; ++l) {
        ci[l - 2] += __popcll(__ballot(lab0 == l)) + __popcll(__ballot(lab1 == l)) +
                     __popcll(__ballot(lab2 == l)) + __popcll(__ballot(lab3 == l));
      }
    }
  }

  // general-P tail: rare slow path (empty for P=409600)
  if (tail && blockIdx.x == 0) {
    for (int p = (ntiles << 10) + (int)threadIdx.x; p < P; p += (int)blockDim.x) {
      int lab = (tp[p] > 0.5f) ? (ip[p] & 7) : 0;
      float kr = kp[p];
      float4 ev = e[p];
      if (lab >= 1 && kr > 0.5f) {
        atomicAdd(&acc[b * ACC_PER_B + (lab - 1) * 4 + 0], ev.x);
        atomicAdd(&acc[b * ACC_PER_B + (lab - 1) * 4 + 1], ev.y);
        atomicAdd(&acc[b * ACC_PER_B + (lab - 1) * 4 + 2], ev.z);
        atomicAdd(&acc[b * ACC_PER_B + (lab - 1) * 4 + 3], ev.w);
        atomicAdd(&acc[b * ACC_PER_B + CK_OFF + lab - 1], 1.f);
      }
      if (lab >= 2) atomicAdd(&acc[b * ACC_PER_B + CI_OFF + lab - 2], 1.f);
    }
    __threadfence();   // order multi-wave tail atomics before the arrive
  }

  // block reduce -> one atomic per slot (all posting lanes are in wave 0)
#pragma unroll
  for (int off = 32; off > 0; off >>= 1) {
    float tsh[28];
#pragma unroll
    for (int k = 0; k < 28; ++k) tsh[k] = __shfl_xor(s[k], off, 64);
#pragma unroll
    for (int k = 0; k < 28; ++k) s[k] += tsh[k];
  }
  if (lane == 0) {
#pragma unroll
    for (int k = 0; k < 28; ++k) redf[wid][k] = s[k];
#pragma unroll
    for (int k = 0; k < 7; ++k) redi[wid][k] = ck[k];
#pragma unroll
    for (int k = 0; k < 6; ++k) redi[wid][7 + k] = ci[k];
  }
  __syncthreads();
  if (threadIdx.x < 28) {
    float v = redf[0][threadIdx.x] + redf[1][threadIdx.x] +
              redf[2][threadIdx.x] + redf[3][threadIdx.x];
    atomicAdd(acc + b * ACC_PER_B + S_OFF + threadIdx.x, v);
  } else if (threadIdx.x >= 32 && threadIdx.x < 32 + 13) {
    int j = threadIdx.x - 32;                  // 0..6 = ck, 7..12 = ci
    int v = redi[0][j] + redi[1][j] + redi[2][j] + redi[3][j];
    atomicAdd(acc + b * ACC_PER_B + CK_OFF + j, (float)v);
  }

  // ===================== grid barrier =====================
  // Release-arrive (orders this wave's atomics), then acquire-spin.
  if (threadIdx.x == 0) {
    unsigned int* cnt = (unsigned int*)(acc + CNT1_IDX);
    __hip_atomic_fetch_add(cnt, 1u, __ATOMIC_ACQ_REL, __HIP_MEMORY_SCOPE_AGENT);
    while (__hip_atomic_load(cnt, __ATOMIC_ACQUIRE, __HIP_MEMORY_SCOPE_AGENT)
           < (unsigned int)nblocks)
      __builtin_amdgcn_s_sleep(2);
  }
  __syncthreads();

  // mu for this block's batch
  if (threadIdx.x < 47)
    accL[threadIdx.x] = __hip_atomic_load(&acc[b * ACC_PER_B + threadIdx.x],
                                          __ATOMIC_RELAXED, __HIP_MEMORY_SCOPE_AGENT);
  __syncthreads();
  if (threadIdx.x < NLAB) {
    int l = threadIdx.x;
    float4 m = make_float4(0.f, 0.f, 0.f, 0.f);
    if (l > 0) {
      float inv = 1.f / fmaxf(accL[CK_OFF + l - 1], 1.f);
      m = make_float4(accL[S_OFF + (l - 1) * 4 + 0] * inv,
                      accL[S_OFF + (l - 1) * 4 + 1] * inv,
                      accL[S_OFF + (l - 1) * 4 + 2] * inv,
                      accL[S_OFF + (l - 1) * 4 + 3] * inv);
    }
    smu_s[l] = m;
  }
  __syncthreads();
  float4 smu[NLAB];
#pragma unroll
  for (int l = 0; l < NLAB; ++l) smu[l] = smu_s[l];

  // ===================== phase 2: aggregation =====================
  float ag[6] = {0.f, 0.f, 0.f, 0.f, 0.f, 0.f};
  {
    int k = 0;
    for (int t = blockIdx.x; t < ntiles; t += GX, ++k) {
      const int p0 = (t << 10) + (wid << 8) + lane;
      int lab0, lab1, lab2, lab3;
      if (k < MAXK) {
        const int lo = (k << 10) + (wid << 8) + lane;
        lab0 = labL[lo]; lab1 = labL[lo + 64];
        lab2 = labL[lo + 128]; lab3 = labL[lo + 192];
      } else {                                 // overflow path (P > GX*MAXK*1024)
        lab0 = (tp[p0] > 0.5f)       ? (ip[p0] & 7)       : 0;
        lab1 = (tp[p0 + 64] > 0.5f)  ? (ip[p0 + 64] & 7)  : 0;
        lab2 = (tp[p0 + 128] > 0.5f) ? (ip[p0 + 128] & 7) : 0;
        lab3 = (tp[p0 + 192] > 0.5f) ? (ip[p0 + 192] & 7) : 0;
      }
      float4 e0 = e[p0];
      float4 e1 = e[p0 + 64];
      float4 e2 = e[p0 + 128];
      float4 e3 = e[p0 + 192];

#pragma unroll
      for (int i = 0; i < 4; ++i) {
        int lab = (i == 0) ? lab0 : (i == 1) ? lab1 : (i == 2) ? lab2 : lab3;
        float4 ev = (i == 0) ? e0 : (i == 1) ? e1 : (i == 2) ? e2 : e3;
        float4 mv = smu[lab];
        float dx = ev.x - mv.x, dy = ev.y - mv.y;
        float dz = ev.z - mv.z, dw = ev.w - mv.w;
        float d = sqrtf(dx * dx + dy * dy + dz * dz + dw * dw);
        float tt = fmaxf(d - 0.5f, 0.f);       // DELTA_V
        float term = logf(fmaf(tt, tt, 1.f));
#pragma unroll
        for (int l = 0; l < 6; ++l) ag[l] += (lab == l + 2) ? term : 0.f;
      }
    }
  }

  if (tail && blockIdx.x == 0) {               // general-P tail
    for (int p = (ntiles << 10) + (int)threadIdx.x; p < P; p += (int)blockDim.x) {
      int lab = (tp[p] > 0.5f) ? (ip[p] & 7) : 0;
      if (lab >= 2) {
        float4 ev = e[p]; float4 mv = smu[lab];
        float dx = ev.x - mv.x, dy = ev.y - mv.y;
        float dz = ev.z - mv.z, dw = ev.w - mv.w;
        float d = sqrtf(dx * dx + dy * dy + dz * dz + dw * dw);
        float tt = fmaxf(d - 0.5f, 0.f);
        atomicAdd(&acc[b * ACC_PER_B + AG_OFF + lab - 2], logf(fmaf(tt, tt, 1.f)));
      }
    }
    __threadfence();
  }

#pragma unroll
  for (int off = 32; off > 0; off >>= 1) {
    float tsh[6];
#pragma unroll
    for (int k = 0; k < 6; ++k) tsh[k] = __shfl_xor(ag[k], off, 64);
#pragma unroll
    for (int k = 0; k < 6; ++k) ag[k] += tsh[k];
  }
  if (lane == 0) {
#pragma unroll
    for (int k = 0; k < 6; ++k) redg[wid][k] = ag[k];
  }
  __syncthreads();
  if (threadIdx.x < 6) {
    float v = redg[0][threadIdx.x] + redg[1][threadIdx.x] +
              redg[2][threadIdx.x] + redg[3][threadIdx.x];
    atomicAdd(acc + b * ACC_PER_B + AG_OFF + threadIdx.x, v);
  }

  // ===================== last-block finalize =====================
  __syncthreads();
  __shared__ int amlast;
  if (threadIdx.x == 0) {
    unsigned int* cnt = (unsigned int*)(acc + CNT2_IDX);
    unsigned int old = __hip_atomic_fetch_add(cnt, 1u, __ATOMIC_ACQ_REL,
                                              __HIP_MEMORY_SCOPE_AGENT);
    amlast = (old == (unsigned int)(nblocks - 1)) ? 1 : 0;
  }
  __syncthreads();
  if (amlast && threadIdx.x < 64) {
    float loss = 0.f;
    if (threadIdx.x < BATCH) {
      const float* a = acc + threadIdx.x * ACC_PER_B;
      float av[47];
#pragma unroll
      for (int k = 0; k < 47; ++k)
        av[k] = __hip_atomic_load(&a[k], __ATOMIC_RELAXED, __HIP_MEMORY_SCOPE_AGENT);
      float mu[NLAB][4];
#pragma unroll
      for (int c = 0; c < 4; ++c) mu[0][c] = 0.f;
#pragma unroll
      for (int l = 1; l < NLAB; ++l) {
        float inv = 1.f / fmaxf(av[CK_OFF + l - 1], 1.f);
#pragma unroll
        for (int c = 0; c < 4; ++c) mu[l][c] = av[S_OFF + (l - 1) * 4 + c] * inv;
      }
      float l_agg = 0.f;
#pragma unroll
      for (int l = 2; l < NLAB; ++l)
        l_agg += av[AG_OFF + l - 2] / fmaxf(av[CI_OFF + l - 2], 1.f);
      l_agg *= (1.f / 6.f);
      float ssum = 0.f;
      for (int i = 1; i < NLAB; ++i)
        for (int j = 1; j < NLAB; ++j) {
          if (i == j) continue;
          float dx = mu[i][0] - mu[j][0], dy = mu[i][1] - mu[j][1];
          float dz = mu[i][2] - mu[j][2], dw = mu[i][3] - mu[j][3];
          float dd = sqrtf(dx * dx + dy * dy + dz * dz + dw * dw);
          float tt = fmaxf(3.0f - dd, 0.f);    // 2*DELTA_D
          ssum += logf(fmaf(tt, tt, 1.f));
        }
      float l_dis = ssum / 42.f;
      float rsum = 0.f;
#pragma unroll
      for (int l = 1; l < NLAB; ++l) {
        float n = sqrtf(mu[l][0] * mu[l][0] + mu[l][1] * mu[l][1] +
                        mu[l][2] * mu[l][2] + mu[l][3] * mu[l][3]);
        rsum += logf(n + 1.f);
      }
      float l_reg = rsum * (0.001f / NLAB);
      loss = l_agg + l_dis + l_reg;
    }
    loss = wave_reduce(loss);
    if (threadIdx.x == 0) out[0] = loss * (1.f / BATCH);   // LOSS_WEIGHT = 1
  }
}

extern "C" void kernel_launch(void* const* d_in, const int* in_sizes, int n_in,
                              void* d_out, int out_size, void* d_ws, size_t ws_size,
                              hipStream_t stream) {
  const float4* emb  = (const float4*)d_in[0];
  const int*    inst = (const int*)d_in[1];
  const float*  ker  = (const float*)d_in[2];
  const float*  tmk  = (const float*)d_in[3];
  float* out = (float*)d_out;

  const int total = in_sizes[1];       // B*H*W
  const int P = total / BATCH;

  float* acc = (float*)d_ws;

  // d_ws re-poisoned to 0xAA each launch: zero accumulators + both counters
  hipMemsetAsync(d_ws, 0, ACC_ZERO_BYTES, stream);

  dim3 grid(GX, BATCH);                // 1024 blocks = 4/CU exact fit (barrier-safe)
  k_fused<<<grid, 256, 0, stream>>>(emb, inst, ker, tmk, acc, out, P, GX * BATCH);
}

// Round 7
// 313.938 us; speedup vs baseline: 1.4159x; 1.4159x over previous
//
#include <hip/hip_runtime.h>
#include <math.h>

#define NLAB 8
#define BATCH 16
// acc layout per batch (floats):
//   [0..27] emb sums L1..7 x4ch | [28..34] cnt_k L1..7 | [35..40] cnt_i L2..7
//   [41..46] agg sums L2..7
#define S_OFF  0
#define CK_OFF 28
#define CI_OFF 35
#define AG_OFF 41
#define ACC_PER_B 48
#define CNT_IDX (BATCH * ACC_PER_B)        // acc[768]: arrival counter (uint)
#define ACC_ZERO_BYTES ((CNT_IDX + 1) * 4)
#define LAB_OFFSET 4096                    // label byte-cache offset in d_ws
#define GX 64                              // 64 x 16 = 1024 blocks

// component select with constant index (post-unroll) — keeps vectors in regs
#define GETI(v, c) ((c) == 0 ? (v).x : (c) == 1 ? (v).y : (c) == 2 ? (v).z : (v).w)
#define GETF(v, c) ((c) == 0 ? (v).x : (c) == 1 ? (v).y : (c) == 2 ? (v).z : (v).w)
#define GETU(v, c) ((c) == 0 ? (v).x : (c) == 1 ? (v).y : (c) == 2 ? (v).z : (v).w)

__device__ __forceinline__ float wave_reduce(float v) {
#pragma unroll
  for (int off = 32; off > 0; off >>= 1) v += __shfl_xor(v, off, 64);
  return v;
}

// ---------------------------------------------------------------------------
// Pass 1. R2's strided pattern (best measured: 64 cache lines per VMEM
// instruction -> max lines-in-flight under the ~1-outstanding-per-wave
// regime), widened to 16 px/thread: 16 emb float4 + 12 aux loads issued as
// one independent batch per iteration. __launch_bounds__(256,2) -> 256-VGPR
// budget so the batch lives in registers (R4 spilled at budget 128).
// ---------------------------------------------------------------------------
__global__ __launch_bounds__(256, 2) void k_accum(
    const float4* __restrict__ emb, const int* __restrict__ inst,
    const float* __restrict__ ker, const float* __restrict__ tmk,
    float* __restrict__ acc, unsigned char* __restrict__ labc,
    int P, int use_cache, int fast)
{
  const int b = blockIdx.y;
  const size_t base = (size_t)b * P;
  const float4* e  = emb + base;
  const int*    ip = inst + base;
  const float*  kp = ker + base;
  const float*  tp = tmk + base;
  unsigned char* lb = labc + base;

  float s[28];
#pragma unroll
  for (int k = 0; k < 28; ++k) s[k] = 0.f;
  int ck[7] = {0, 0, 0, 0, 0, 0, 0};
  int ci[6] = {0, 0, 0, 0, 0, 0};

  const int tid = blockIdx.x * blockDim.x + threadIdx.x;
  const int nthreads = gridDim.x * blockDim.x;

  if (fast) {
    const int nu = P >> 4;                   // 16-px units
    const int4*   ip4 = (const int4*)ip;
    const float4* kp4 = (const float4*)kp;
    const float4* tp4 = (const float4*)tp;
    uint4* lb4 = (uint4*)lb;

    for (int u = tid; u < nu; u += nthreads) {
      // ---- one independent load batch: 28 VMEM, no use before all issued ----
      int4   iv[4]; float4 kv[4], tv[4]; float4 ev[16];
#pragma unroll
      for (int a = 0; a < 4; ++a) iv[a] = ip4[u * 4 + a];
#pragma unroll
      for (int a = 0; a < 4; ++a) kv[a] = kp4[u * 4 + a];
#pragma unroll
      for (int a = 0; a < 4; ++a) tv[a] = tp4[u * 4 + a];
#pragma unroll
      for (int j = 0; j < 16; ++j) ev[j] = e[u * 16 + j];

      int lab[16], lk[16];
#pragma unroll
      for (int j = 0; j < 16; ++j) {
        int   v = GETI(iv[j >> 2], j & 3);
        float q = GETF(kv[j >> 2], j & 3);
        float t = GETF(tv[j >> 2], j & 3);
        lab[j] = (t > 0.5f) ? (v & 7) : 0;
        lk[j]  = (q > 0.5f) ? lab[j] : 8;    // 8 = sentinel, matches no l
      }
      if (use_cache) {
        uint4 pk;
        pk.x = (unsigned)lab[0]  | ((unsigned)lab[1]  << 8) | ((unsigned)lab[2]  << 16) | ((unsigned)lab[3]  << 24);
        pk.y = (unsigned)lab[4]  | ((unsigned)lab[5]  << 8) | ((unsigned)lab[6]  << 16) | ((unsigned)lab[7]  << 24);
        pk.z = (unsigned)lab[8]  | ((unsigned)lab[9]  << 8) | ((unsigned)lab[10] << 16) | ((unsigned)lab[11] << 24);
        pk.w = (unsigned)lab[12] | ((unsigned)lab[13] << 8) | ((unsigned)lab[14] << 16) | ((unsigned)lab[15] << 24);
        lb4[u] = pk;
      }
#pragma unroll
      for (int l = 1; l < NLAB; ++l) {
        int c = 0;
        const int o = (l - 1) * 4;
#pragma unroll
        for (int j = 0; j < 16; ++j) {
          bool h = (lk[j] == l);
          c += __popcll(__ballot(h));        // wave-level count (SALU side)
          float m = h ? 1.f : 0.f;
          s[o + 0] = fmaf(m, ev[j].x, s[o + 0]);
          s[o + 1] = fmaf(m, ev[j].y, s[o + 1]);
          s[o + 2] = fmaf(m, ev[j].z, s[o + 2]);
          s[o + 3] = fmaf(m, ev[j].w, s[o + 3]);
        }
        ck[l - 1] += c;
      }
#pragma unroll
      for (int l = 2; l < NLAB; ++l) {
        int c = 0;
#pragma unroll
        for (int j = 0; j < 16; ++j) c += __popcll(__ballot(lab[j] == l));
        ci[l - 2] += c;
      }
    }
    // tail px (P % 16): rare slow path, direct atomics
    const int p0 = nu << 4;
    for (int p = p0 + tid; p < P; p += nthreads) {
      int lab = (tp[p] > 0.5f) ? (ip[p] & 7) : 0;
      float kr = kp[p];
      float4 ev = e[p];
      if (use_cache) lb[p] = (unsigned char)lab;
      if (lab >= 1 && kr > 0.5f) {
        atomicAdd(&acc[b * ACC_PER_B + (lab - 1) * 4 + 0], ev.x);
        atomicAdd(&acc[b * ACC_PER_B + (lab - 1) * 4 + 1], ev.y);
        atomicAdd(&acc[b * ACC_PER_B + (lab - 1) * 4 + 2], ev.z);
        atomicAdd(&acc[b * ACC_PER_B + (lab - 1) * 4 + 3], ev.w);
        atomicAdd(&acc[b * ACC_PER_B + CK_OFF + lab - 1], 1.f);
      }
      if (lab >= 2) atomicAdd(&acc[b * ACC_PER_B + CI_OFF + lab - 2], 1.f);
    }
  } else {
    // correctness-only scalar fallback (never hit for the bench shape)
    for (int p = tid; p < P; p += nthreads) {
      int lab = (tp[p] > 0.5f) ? (ip[p] & 7) : 0;
      float kr = kp[p];
      float4 ev = e[p];
      if (use_cache) lb[p] = (unsigned char)lab;
      if (lab >= 1 && kr > 0.5f) {
        atomicAdd(&acc[b * ACC_PER_B + (lab - 1) * 4 + 0], ev.x);
        atomicAdd(&acc[b * ACC_PER_B + (lab - 1) * 4 + 1], ev.y);
        atomicAdd(&acc[b * ACC_PER_B + (lab - 1) * 4 + 2], ev.z);
        atomicAdd(&acc[b * ACC_PER_B + (lab - 1) * 4 + 3], ev.w);
        atomicAdd(&acc[b * ACC_PER_B + CK_OFF + lab - 1], 1.f);
      }
      if (lab >= 2) atomicAdd(&acc[b * ACC_PER_B + CI_OFF + lab - 2], 1.f);
    }
  }

  // lane 0 holds exact wave totals for counts (ballot); floats wave-reduced.
  const int lane = threadIdx.x & 63;
  const int wid  = threadIdx.x >> 6;
#pragma unroll
  for (int off = 32; off > 0; off >>= 1) {
    float tsh[28];
#pragma unroll
    for (int k = 0; k < 28; ++k) tsh[k] = __shfl_xor(s[k], off, 64);
#pragma unroll
    for (int k = 0; k < 28; ++k) s[k] += tsh[k];
  }
  __shared__ float redf[4][28];
  __shared__ int   redi[4][13];
  if (lane == 0) {
#pragma unroll
    for (int k = 0; k < 28; ++k) redf[wid][k] = s[k];
#pragma unroll
    for (int k = 0; k < 7; ++k) redi[wid][k] = ck[k];
#pragma unroll
    for (int k = 0; k < 6; ++k) redi[wid][7 + k] = ci[k];
  }
  __syncthreads();
  if (threadIdx.x < 28) {
    float v = redf[0][threadIdx.x] + redf[1][threadIdx.x] +
              redf[2][threadIdx.x] + redf[3][threadIdx.x];
    atomicAdd(acc + b * ACC_PER_B + S_OFF + threadIdx.x, v);
  } else if (threadIdx.x >= 32 && threadIdx.x < 32 + 13) {
    int j = threadIdx.x - 32;                // 0..6 = ck, 7..12 = ci
    int v = redi[0][j] + redi[1][j] + redi[2][j] + redi[3][j];
    atomicAdd(acc + b * ACC_PER_B + CK_OFF + j, (float)v);
  }
}

// ---------------------------------------------------------------------------
// Pass 2 + folded finalize. Same wide-batch pattern: 16 emb float4 + 1 uint4
// of cached labels per iteration.
// ---------------------------------------------------------------------------
__global__ __launch_bounds__(256, 2) void k_agg(
    const float4* __restrict__ emb, const int* __restrict__ inst,
    const float* __restrict__ tmk, const unsigned char* __restrict__ labc,
    float* __restrict__ acc, float* __restrict__ out,
    int P, int use_cache, int fast, int nblocks)
{
  const int b = blockIdx.y;
  const size_t base = (size_t)b * P;
  __shared__ float4 smu_s[NLAB];
  const float* accB = acc + b * ACC_PER_B;
  if (threadIdx.x < NLAB) {
    int l = threadIdx.x;
    float4 m = make_float4(0.f, 0.f, 0.f, 0.f);
    if (l > 0) {
      float inv = 1.f / fmaxf(accB[CK_OFF + l - 1], 1.f);
      m = make_float4(accB[S_OFF + (l - 1) * 4 + 0] * inv,
                      accB[S_OFF + (l - 1) * 4 + 1] * inv,
                      accB[S_OFF + (l - 1) * 4 + 2] * inv,
                      accB[S_OFF + (l - 1) * 4 + 3] * inv);
    }
    smu_s[l] = m;
  }
  __syncthreads();
  float4 smu[NLAB];
#pragma unroll
  for (int l = 0; l < NLAB; ++l) smu[l] = smu_s[l];

  const float4* e  = emb + base;
  const int*    ip = inst + base;
  const float*  tp = tmk + base;
  const unsigned char* lb = labc + base;

  float ag[6] = {0.f, 0.f, 0.f, 0.f, 0.f, 0.f};
  const int tid = blockIdx.x * blockDim.x + threadIdx.x;
  const int nthreads = gridDim.x * blockDim.x;

  if (fast) {
    const int nu = P >> 4;
    const uint4* lb4 = (const uint4*)lb;
    const int4*   ip4 = (const int4*)ip;
    const float4* tp4 = (const float4*)tp;

    for (int u = tid; u < nu; u += nthreads) {
      float4 ev[16];
#pragma unroll
      for (int j = 0; j < 16; ++j) ev[j] = e[u * 16 + j];
      int lab[16];
      if (use_cache) {
        uint4 lq = lb4[u];
#pragma unroll
        for (int j = 0; j < 16; ++j)
          lab[j] = (GETU(lq, j >> 2) >> ((j & 3) * 8)) & 7;
      } else {
        int4 iv[4]; float4 tv[4];
#pragma unroll
        for (int a = 0; a < 4; ++a) iv[a] = ip4[u * 4 + a];
#pragma unroll
        for (int a = 0; a < 4; ++a) tv[a] = tp4[u * 4 + a];
#pragma unroll
        for (int j = 0; j < 16; ++j) {
          int   v = GETI(iv[j >> 2], j & 3);
          float t = GETF(tv[j >> 2], j & 3);
          lab[j] = (t > 0.5f) ? (v & 7) : 0;
        }
      }
#pragma unroll
      for (int j = 0; j < 16; ++j) {
        float4 mv = smu[lab[j]];
        float dx = ev[j].x - mv.x, dy = ev[j].y - mv.y;
        float dz = ev[j].z - mv.z, dw = ev[j].w - mv.w;
        float d = sqrtf(dx * dx + dy * dy + dz * dz + dw * dw);
        float tt = fmaxf(d - 0.5f, 0.f);     // DELTA_V
        float term = logf(fmaf(tt, tt, 1.f));
#pragma unroll
        for (int l = 0; l < 6; ++l) ag[l] += (lab[j] == l + 2) ? term : 0.f;
      }
    }
    const int p0 = nu << 4;                  // tail px
    for (int p = p0 + tid; p < P; p += nthreads) {
      int lab = (tp[p] > 0.5f) ? (ip[p] & 7) : 0;
      if (lab >= 2) {
        float4 ev = e[p]; float4 mv = smu[lab];
        float dx = ev.x - mv.x, dy = ev.y - mv.y;
        float dz = ev.z - mv.z, dw = ev.w - mv.w;
        float d = sqrtf(dx * dx + dy * dy + dz * dz + dw * dw);
        float tt = fmaxf(d - 0.5f, 0.f);
        atomicAdd(&acc[b * ACC_PER_B + AG_OFF + lab - 2], logf(fmaf(tt, tt, 1.f)));
      }
    }
  } else {
    for (int p = tid; p < P; p += nthreads) {
      int lab = (tp[p] > 0.5f) ? (ip[p] & 7) : 0;
      if (lab >= 2) {
        float4 ev = e[p]; float4 mv = smu[lab];
        float dx = ev.x - mv.x, dy = ev.y - mv.y;
        float dz = ev.z - mv.z, dw = ev.w - mv.w;
        float d = sqrtf(dx * dx + dy * dy + dz * dz + dw * dw);
        float tt = fmaxf(d - 0.5f, 0.f);
        atomicAdd(&acc[b * ACC_PER_B + AG_OFF + lab - 2], logf(fmaf(tt, tt, 1.f)));
      }
    }
  }

  const int lane = threadIdx.x & 63;
  const int wid  = threadIdx.x >> 6;
#pragma unroll
  for (int off = 32; off > 0; off >>= 1) {
    float tsh[6];
#pragma unroll
    for (int k = 0; k < 6; ++k) tsh[k] = __shfl_xor(ag[k], off, 64);
#pragma unroll
    for (int k = 0; k < 6; ++k) ag[k] += tsh[k];
  }
  __shared__ float redg[4][6];
  if (lane == 0) {
#pragma unroll
    for (int k = 0; k < 6; ++k) redg[wid][k] = ag[k];
  }
  __syncthreads();
  if (threadIdx.x < 6) {
    float v = redg[0][threadIdx.x] + redg[1][threadIdx.x] +
              redg[2][threadIdx.x] + redg[3][threadIdx.x];
    atomicAdd(acc + b * ACC_PER_B + AG_OFF + threadIdx.x, v);
  }

  // ---- folded finalize: last-arriving block computes the loss ----
  __syncthreads();
  __shared__ int amlast;
  if (threadIdx.x == 0) {
    unsigned int* cnt = (unsigned int*)(acc + CNT_IDX);
    unsigned int old = __hip_atomic_fetch_add(cnt, 1u, __ATOMIC_ACQ_REL,
                                              __HIP_MEMORY_SCOPE_AGENT);
    amlast = (old == (unsigned int)(nblocks - 1)) ? 1 : 0;
  }
  __syncthreads();
  if (amlast && threadIdx.x < 64) {
    float loss = 0.f;
    if (threadIdx.x < BATCH) {
      const float* a = acc + threadIdx.x * ACC_PER_B;
      float av[47];
#pragma unroll
      for (int k = 0; k < 47; ++k)
        av[k] = __hip_atomic_load(&a[k], __ATOMIC_RELAXED, __HIP_MEMORY_SCOPE_AGENT);
      float mu[NLAB][4];
#pragma unroll
      for (int c = 0; c < 4; ++c) mu[0][c] = 0.f;
#pragma unroll
      for (int l = 1; l < NLAB; ++l) {
        float inv = 1.f / fmaxf(av[CK_OFF + l - 1], 1.f);
#pragma unroll
        for (int c = 0; c < 4; ++c) mu[l][c] = av[S_OFF + (l - 1) * 4 + c] * inv;
      }
      float l_agg = 0.f;
#pragma unroll
      for (int l = 2; l < NLAB; ++l)
        l_agg += av[AG_OFF + l - 2] / fmaxf(av[CI_OFF + l - 2], 1.f);
      l_agg *= (1.f / 6.f);
      float ssum = 0.f;
      for (int i = 1; i < NLAB; ++i)
        for (int j = 1; j < NLAB; ++j) {
          if (i == j) continue;
          float dx = mu[i][0] - mu[j][0], dy = mu[i][1] - mu[j][1];
          float dz = mu[i][2] - mu[j][2], dw = mu[i][3] - mu[j][3];
          float dd = sqrtf(dx * dx + dy * dy + dz * dz + dw * dw);
          float tt = fmaxf(3.0f - dd, 0.f);  // 2*DELTA_D
          ssum += logf(fmaf(tt, tt, 1.f));
        }
      float l_dis = ssum / 42.f;
      float rsum = 0.f;
#pragma unroll
      for (int l = 1; l < NLAB; ++l) {
        float n = sqrtf(mu[l][0] * mu[l][0] + mu[l][1] * mu[l][1] +
                        mu[l][2] * mu[l][2] + mu[l][3] * mu[l][3]);
        rsum += logf(n + 1.f);
      }
      float l_reg = rsum * (0.001f / NLAB);
      loss = l_agg + l_dis + l_reg;
    }
    loss = wave_reduce(loss);
    if (threadIdx.x == 0) out[0] = loss * (1.f / BATCH);   // LOSS_WEIGHT = 1
  }
}

extern "C" void kernel_launch(void* const* d_in, const int* in_sizes, int n_in,
                              void* d_out, int out_size, void* d_ws, size_t ws_size,
                              hipStream_t stream) {
  const float4* emb  = (const float4*)d_in[0];
  const int*    inst = (const int*)d_in[1];
  const float*  ker  = (const float*)d_in[2];
  const float*  tmk  = (const float*)d_in[3];
  float* out = (float*)d_out;

  const int total = in_sizes[1];       // B*H*W
  const int P = total / BATCH;

  float* acc = (float*)d_ws;
  unsigned char* labc = (unsigned char*)d_ws + LAB_OFFSET;
  const size_t need = (size_t)LAB_OFFSET + (size_t)total;
  const int use_cache = (ws_size >= need) ? 1 : 0;
  // fast path needs per-batch 16-px alignment for int4/float4/uint4 units
  const int fast = ((P & 15) == 0) ? 1 : 0;

  // d_ws re-poisoned to 0xAA each launch: zero accumulators + arrival counter
  hipMemsetAsync(d_ws, 0, ACC_ZERO_BYTES, stream);

  dim3 grid(GX, BATCH);                // 1024 blocks, 2/CU resident (dynamic)
  k_accum<<<grid, 256, 0, stream>>>(emb, inst, ker, tmk, acc, labc, P,
                                    use_cache, fast);
  k_agg  <<<grid, 256, 0, stream>>>(emb, inst, tmk, labc, acc, out, P,
                                    use_cache, fast, GX * BATCH);
}